// Round 7
// baseline (155.206 us; speedup 1.0000x reference)
//
#include <hip/hip_runtime.h>

#define B_ 2
#define H_ 16
#define N_ 2048
#define D_ 64
#define NH_ (B_*H_)            // 32 heads
#define ROWS_ (NH_*N_)         // 65536 rows per tensor
#define KVB 64
#define NT (N_/KVB)            // 32 kv tiles
#define LOG2E 1.4426950408889634f
#define QSCALE (0.25f * LOG2E)

typedef _Float16 f16;
typedef _Float16 f16x2 __attribute__((ext_vector_type(2)));
typedef _Float16 f16x4 __attribute__((ext_vector_type(4)));
typedef _Float16 f16x8 __attribute__((ext_vector_type(8)));
typedef __fp16 h16x2 __attribute__((ext_vector_type(2)));   // builtin return type
typedef float f32x4 __attribute__((ext_vector_type(4)));

typedef __attribute__((address_space(1))) const void g_void;
typedef __attribute__((address_space(3))) void l_void;

__device__ __forceinline__ void gl_lds16(const void* g, void* l) {
  __builtin_amdgcn_global_load_lds((g_void*)g, (l_void*)l, 16, 0, 0);
}

__device__ __forceinline__ f16x2 cvt_pk(float a, float b) {
  return __builtin_bit_cast(f16x2, __builtin_amdgcn_cvt_pkrtz(a, b));
}

__device__ __forceinline__ float dot2acc(f16x2 a, f16x2 b, float c) {
#if __has_builtin(__builtin_amdgcn_fdot2)
  return __builtin_amdgcn_fdot2(__builtin_bit_cast(h16x2, a),
                                __builtin_bit_cast(h16x2, b), c, false);
#else
  return c + (float)a[0] * (float)b[0] + (float)a[1] * (float)b[1];
#endif
}

// ---------------------------------------------------------------------------
// Prep: blocks [0,1024): V^T via in-register 4x4 transpose (no LDS).
//       blocks [1024,2048): q,k f32->f16 (+bias) grid-stride, 8 lanes/row.
// qh = f16(0.25*log2e * q); bias = masked ? -1e30 : -|k|^2 * log2e
// ---------------------------------------------------------------------------
__global__ __launch_bounds__(256) void prep_all(
    const float* __restrict__ q, const float* __restrict__ k,
    const float* __restrict__ v, const void* __restrict__ mask,
    f16* __restrict__ qh, f16* __restrict__ kh, f16* __restrict__ vt,
    float* __restrict__ bias) {
  int tid = threadIdx.x;
  if (blockIdx.x < 1024) {
    int head = blockIdx.x >> 5;
    int n0 = (blockIdx.x & 31) << 6;
    int e = tid & 15, gq = tid >> 4;
    const float* src = v + ((long)head * N_ + n0 + e * 4) * D_ + gq * 4;
    f32x4 r0 = *(const f32x4*)(src);
    f32x4 r1 = *(const f32x4*)(src + D_);
    f32x4 r2 = *(const f32x4*)(src + 2 * D_);
    f32x4 r3 = *(const f32x4*)(src + 3 * D_);
    f16* dst = vt + (long)head * D_ * N_ + n0 + e * 4;
#pragma unroll
    for (int c = 0; c < 4; ++c) {
      f16x4 y;
      y[0] = (f16)r0[c]; y[1] = (f16)r1[c]; y[2] = (f16)r2[c]; y[3] = (f16)r3[c];
      *(f16x4*)(dst + (long)(gq * 4 + c) * N_) = y;
    }
  } else {
    int wid = (blockIdx.x - 1024) * 4 + (tid >> 6);
    int lane = tid & 63;
    int r8 = lane >> 3, e = lane & 7;
    const unsigned* mw = (const unsigned*)mask;
    bool bytes_mode = __any(mw[lane] > 1u);
#pragma unroll
    for (int trip = 0; trip < 4; ++trip) {
      long grow = ((long)(trip * 4096 + wid)) * 8 + r8;
      bool isK = grow >= ROWS_;
      long row = isK ? grow - ROWS_ : grow;
      const float* s = (isK ? k : q) + row * D_ + e * 8;
      f32x4 x0 = *(const f32x4*)s;
      f32x4 x1 = *(const f32x4*)(s + 4);
      float scl = isK ? 1.0f : QSCALE;
      f16x8 hv;
#pragma unroll
      for (int c = 0; c < 4; ++c) { hv[c] = (f16)(x0[c] * scl); hv[4 + c] = (f16)(x1[c] * scl); }
      *(f16x8*)((isK ? kh : qh) + row * D_ + e * 8) = hv;
      if (isK) {
        float sq = x0[0]*x0[0] + x0[1]*x0[1] + x0[2]*x0[2] + x0[3]*x0[3]
                 + x1[0]*x1[0] + x1[1]*x1[1] + x1[2]*x1[2] + x1[3]*x1[3];
        sq += __shfl_xor(sq, 1); sq += __shfl_xor(sq, 2); sq += __shfl_xor(sq, 4);
        if (e == 0) {
          int b = (int)(row >> 15);
          int n = (int)(row & (N_ - 1));
          int mv = bytes_mode ? (int)((const unsigned char*)mask)[b * N_ + n]
                              : ((const int*)mask)[b * N_ + n];
          bias[row] = mv ? -1e30f : -sq * LOG2E;
        }
      }
    }
  }
}

// ---------------------------------------------------------------------------
// Main: flash attention, swapped-operand QK^T (bias as MFMA C-in),
// in-register softmax with defer-max, packed f16 cvt + fdot2 row-sum,
// per-block KV-tile stagger, hoisted swizzled offsets.
// Block = 4 waves x 16 q-rows. LDS 40KB -> 4 blk/CU.
// ---------------------------------------------------------------------------
__global__ __launch_bounds__(256, 4) void attend_main(
    const f16* __restrict__ qh, const f16* __restrict__ kh,
    const f16* __restrict__ vt, const float* __restrict__ bias,
    float* __restrict__ out) {
  __shared__ f16 Kt[2][4096];
  __shared__ f16 Vt[2][4096];
  __shared__ f16 Pb[4][1024];

  int tid = threadIdx.x;
  int w = tid >> 6, lane = tid & 63;
  int j = lane & 15, g = lane >> 4;

  int bid = (blockIdx.x & 7) * 128 + (blockIdx.x >> 3);
  int head = bid >> 5;
  int qt = bid & 31;
  int qrow0 = qt * 64 + w * 16;
  int off = ((bid >> 5) & 3) * 8;          // co-resident blocks differ in phase

  const f16* qbase = qh + ((long)head * N_ + qrow0 + j) * D_;
  f16x8 qf0 = *(const f16x8*)(qbase + g * 8);
  f16x8 qf1 = *(const f16x8*)(qbase + 32 + g * 8);

  const char* kg = (const char*)(kh + (long)head * N_ * D_);
  const char* vg = (const char*)(vt + (long)head * D_ * N_);
  const float* bb = bias + (long)head * N_ + g * 4;

  int ko0[4], ko1[4];
#pragma unroll
  for (int x = 0; x < 4; ++x) {
    int rk = x * 16 + j;
    int swk = (rk & 7) << 4;
    ko0[x] = ((rk << 7) + g * 16) ^ swk;
    ko1[x] = ((rk << 7) + 64 + g * 16) ^ swk;
  }
  int pswz = (j & 7) << 4;
  int pw0 = ((j << 7) + g * 8) ^ pswz;
  int pr0 = ((j << 7) + g * 16) ^ pswz;
  int pr1 = ((j << 7) + 64 + g * 16) ^ pswz;

  f32x4 O0 = {0.f,0.f,0.f,0.f}, O1 = {0.f,0.f,0.f,0.f};
  f32x4 O2 = {0.f,0.f,0.f,0.f}, O3 = {0.f,0.f,0.f,0.f};
  float m = -1e30f, l = 0.f;

  auto stage = [&](int buf, int t) {
    int kv = t * KVB;
    if (w < 2) {
      const char* src = kg + (size_t)kv * 128;
      char* lb = (char*)&Kt[buf][0];
#pragma unroll
      for (int c = 0; c < 4; ++c) {
        int chunk = w * 4 + c;
        int o = chunk * 1024 + lane * 16;
        int p = o ^ (((o >> 7) & 7) << 4);
        gl_lds16(src + p, lb + chunk * 1024);
      }
    } else {
      const char* src = vg + (size_t)kv * 2;
      char* lb = (char*)&Vt[buf][0];
#pragma unroll
      for (int c = 0; c < 4; ++c) {
        int chunk = (w - 2) * 4 + c;
        int o = chunk * 1024 + lane * 16;
        int p = o ^ (((o >> 7) & 7) << 4);
        gl_lds16(src + (size_t)(p >> 7) * (N_ * 2) + (p & 127), lb + chunk * 1024);
      }
    }
  };

  f32x4 bnx[4];
#pragma unroll
  for (int jt = 0; jt < 4; ++jt) bnx[jt] = *(const f32x4*)(bb + off * KVB + jt * 16);

  stage(0, off);
  __syncthreads();
  int cur = 0;

  for (int t = 0; t < NT; ++t) {
    int tt = (t + off) & (NT - 1);
    int tn = (tt + 1) & (NT - 1);
    if (t + 1 < NT) stage(cur ^ 1, tn);    // async prefetch of next K/V tile

    const char* Kc = (const char*)&Kt[cur][0];
    const char* Vc = (const char*)&Vt[cur][0];

    // ---- QK^T (A=K, B=Q); bias enters as the MFMA accumulator init ----
    f32x4 sA[4];
    __builtin_amdgcn_s_setprio(1);
#pragma unroll
    for (int jt = 0; jt < 4; ++jt) {
      f16x8 k0 = *(const f16x8*)(Kc + ko0[jt]);
      f16x8 k1 = *(const f16x8*)(Kc + ko1[jt]);
      f32x4 a = __builtin_amdgcn_mfma_f32_16x16x32_f16(k0, qf0, bnx[jt], 0, 0, 0);
      sA[jt]  = __builtin_amdgcn_mfma_f32_16x16x32_f16(k1, qf1, a, 0, 0, 0);
    }
    __builtin_amdgcn_s_setprio(0);

    // prefetch next-tile bias during softmax/PV window
    if (t + 1 < NT) {
#pragma unroll
      for (int jt = 0; jt < 4; ++jt)
        bnx[jt] = *(const f32x4*)(bb + tn * KVB + jt * 16);
    }

    // ---- in-register online softmax (one q-row per lane), defer-max THR=8 ----
    float tm;
    {
      float a0 = fmaxf(fmaxf(sA[0][0], sA[0][1]), fmaxf(sA[0][2], sA[0][3]));
      float a1 = fmaxf(fmaxf(sA[1][0], sA[1][1]), fmaxf(sA[1][2], sA[1][3]));
      float a2 = fmaxf(fmaxf(sA[2][0], sA[2][1]), fmaxf(sA[2][2], sA[2][3]));
      float a3 = fmaxf(fmaxf(sA[3][0], sA[3][1]), fmaxf(sA[3][2], sA[3][3]));
      tm = fmaxf(fmaxf(a0, a1), fmaxf(a2, a3));
    }
    tm = fmaxf(tm, __shfl_xor(tm, 16));
    tm = fmaxf(tm, __shfl_xor(tm, 32));

    bool fastok = (tm - m <= 8.0f) && (m > -1e29f);
    if (!__all(fastok)) {
      float mn = fmaxf(m, tm);
      float sc = __builtin_amdgcn_exp2f(m - mn);
      m = mn;
      l *= sc;
#pragma unroll
      for (int r = 0; r < 4; ++r) {
        float scr = __shfl(sc, g * 4 + r);
        O0[r] *= scr; O1[r] *= scr; O2[r] *= scr; O3[r] *= scr;
      }
    }

    // exp -> packed f16 P; row-sum via dot2 on the f16 values (consistent w/ PV)
    f16x2 pk[8];
    float rsum = 0.f;
    const f16x2 ones = {(f16)1.0f, (f16)1.0f};
#pragma unroll
    for (int jt = 0; jt < 4; ++jt) {
      float p0 = __builtin_amdgcn_exp2f(sA[jt][0] - m);
      float p1 = __builtin_amdgcn_exp2f(sA[jt][1] - m);
      float p2 = __builtin_amdgcn_exp2f(sA[jt][2] - m);
      float p3 = __builtin_amdgcn_exp2f(sA[jt][3] - m);
      pk[jt * 2 + 0] = cvt_pk(p0, p1);
      pk[jt * 2 + 1] = cvt_pk(p2, p3);
      rsum = dot2acc(pk[jt * 2 + 0], ones, rsum);
      rsum = dot2acc(pk[jt * 2 + 1], ones, rsum);
    }
    rsum += __shfl_xor(rsum, 16);
    rsum += __shfl_xor(rsum, 32);
    l += rsum;

    // ---- P -> LDS (one b64 per jt) then A-fragments ----
    char* Pw = (char*)&Pb[w][0];
#pragma unroll
    for (int jt = 0; jt < 4; ++jt) {
      f16x4 pv_ = __builtin_shufflevector(pk[jt * 2], pk[jt * 2 + 1], 0, 1, 2, 3);
      *(f16x4*)(Pw + (pw0 ^ (jt * 32))) = pv_;
    }
    f16x8 pf0 = *(const f16x8*)(Pw + pr0);
    f16x8 pf1 = *(const f16x8*)(Pw + pr1);

    // ---- PV ----
    __builtin_amdgcn_s_setprio(1);
#pragma unroll
    for (int dt = 0; dt < 4; ++dt) {
      f16x8 v0 = *(const f16x8*)(Vc + ko0[dt]);
      f16x8 v1 = *(const f16x8*)(Vc + ko1[dt]);
      f32x4* Od = (dt == 0) ? &O0 : (dt == 1) ? &O1 : (dt == 2) ? &O2 : &O3;
      *Od = __builtin_amdgcn_mfma_f32_16x16x32_f16(pf0, v0, *Od, 0, 0, 0);
      *Od = __builtin_amdgcn_mfma_f32_16x16x32_f16(pf1, v1, *Od, 0, 0, 0);
    }
    __builtin_amdgcn_s_setprio(0);

    __syncthreads();
    cur ^= 1;
  }

  // ---- epilogue ----
  float* ob = out + ((long)head * N_ + qrow0 + g * 4) * D_ + j;
#pragma unroll
  for (int r = 0; r < 4; ++r) {
    float inv = 1.0f / __shfl(l, g * 4 + r);
    float* o2 = ob + (long)r * D_;
    o2[0]  = O0[r] * inv;
    o2[16] = O1[r] * inv;
    o2[32] = O2[r] * inv;
    o2[48] = O3[r] * inv;
  }
}

extern "C" void kernel_launch(void* const* d_in, const int* in_sizes, int n_in,
                              void* d_out, int out_size, void* d_ws, size_t ws_size,
                              hipStream_t stream) {
  const float* q = (const float*)d_in[0];
  const float* k = (const float*)d_in[1];
  const float* v = (const float*)d_in[2];
  const void* mask = d_in[3];

  char* ws = (char*)d_ws;
  f16*   qh   = (f16*)ws;
  f16*   kh   = (f16*)(ws + (8u  << 20));
  f16*   vt   = (f16*)(ws + (16u << 20));
  float* bias = (float*)(ws + (24u << 20));
  float* out  = (float*)d_out;

  prep_all<<<dim3(2048), dim3(256), 0, stream>>>(q, k, v, mask, qh, kh, vt, bias);
  attend_main<<<dim3(NH_ * (N_ / 64)), dim3(256), 0, stream>>>(qh, kh, vt, bias, out);
}

// Round 8
// 151.104 us; speedup vs baseline: 1.0271x; 1.0271x over previous
//
#include <hip/hip_runtime.h>

#define B_ 2
#define H_ 16
#define N_ 2048
#define D_ 64
#define NH_ (B_*H_)            // 32 heads
#define ROWS_ (NH_*N_)         // 65536 rows per tensor
#define KVB 64
#define NT (N_/KVB)            // 32 kv tiles
#define LOG2E 1.4426950408889634f
#define QSCALE (0.25f * LOG2E)

typedef _Float16 f16;
typedef _Float16 f16x2 __attribute__((ext_vector_type(2)));
typedef _Float16 f16x4 __attribute__((ext_vector_type(4)));
typedef _Float16 f16x8 __attribute__((ext_vector_type(8)));
typedef __fp16 h16x2 __attribute__((ext_vector_type(2)));   // builtin return type
typedef float f32x4 __attribute__((ext_vector_type(4)));

typedef __attribute__((address_space(1))) const void g_void;
typedef __attribute__((address_space(3))) void l_void;

__device__ __forceinline__ void gl_lds16(const void* g, void* l) {
  __builtin_amdgcn_global_load_lds((g_void*)g, (l_void*)l, 16, 0, 0);
}

__device__ __forceinline__ f16x2 cvt_pk(float a, float b) {
  return __builtin_bit_cast(f16x2, __builtin_amdgcn_cvt_pkrtz(a, b));
}

__device__ __forceinline__ float dot2acc(f16x2 a, f16x2 b, float c) {
#if __has_builtin(__builtin_amdgcn_fdot2)
  return __builtin_amdgcn_fdot2(__builtin_bit_cast(h16x2, a),
                                __builtin_bit_cast(h16x2, b), c, false);
#else
  return c + (float)a[0] * (float)b[0] + (float)a[1] * (float)b[1];
#endif
}

// ---------------------------------------------------------------------------
// Prep: blocks [0,1024): V^T via in-register 4x4 transpose (no LDS).
//       blocks [1024,2048): q,k f32->f16 (+bias) grid-stride, 8 lanes/row.
// qh = f16(0.25*log2e * q); bias = masked ? -1e30 : -|k|^2 * log2e
// ---------------------------------------------------------------------------
__global__ __launch_bounds__(256) void prep_all(
    const float* __restrict__ q, const float* __restrict__ k,
    const float* __restrict__ v, const void* __restrict__ mask,
    f16* __restrict__ qh, f16* __restrict__ kh, f16* __restrict__ vt,
    float* __restrict__ bias) {
  int tid = threadIdx.x;
  if (blockIdx.x < 1024) {
    int head = blockIdx.x >> 5;
    int n0 = (blockIdx.x & 31) << 6;
    int e = tid & 15, gq = tid >> 4;
    const float* src = v + ((long)head * N_ + n0 + e * 4) * D_ + gq * 4;
    f32x4 r0 = *(const f32x4*)(src);
    f32x4 r1 = *(const f32x4*)(src + D_);
    f32x4 r2 = *(const f32x4*)(src + 2 * D_);
    f32x4 r3 = *(const f32x4*)(src + 3 * D_);
    f16* dst = vt + (long)head * D_ * N_ + n0 + e * 4;
#pragma unroll
    for (int c = 0; c < 4; ++c) {
      f16x4 y;
      y[0] = (f16)r0[c]; y[1] = (f16)r1[c]; y[2] = (f16)r2[c]; y[3] = (f16)r3[c];
      *(f16x4*)(dst + (long)(gq * 4 + c) * N_) = y;
    }
  } else {
    int wid = (blockIdx.x - 1024) * 4 + (tid >> 6);
    int lane = tid & 63;
    int r8 = lane >> 3, e = lane & 7;
    const unsigned* mw = (const unsigned*)mask;
    bool bytes_mode = __any(mw[lane] > 1u);
#pragma unroll
    for (int trip = 0; trip < 4; ++trip) {
      long grow = ((long)(trip * 4096 + wid)) * 8 + r8;
      bool isK = grow >= ROWS_;
      long row = isK ? grow - ROWS_ : grow;
      const float* s = (isK ? k : q) + row * D_ + e * 8;
      f32x4 x0 = *(const f32x4*)s;
      f32x4 x1 = *(const f32x4*)(s + 4);
      float scl = isK ? 1.0f : QSCALE;
      f16x8 hv;
#pragma unroll
      for (int c = 0; c < 4; ++c) { hv[c] = (f16)(x0[c] * scl); hv[4 + c] = (f16)(x1[c] * scl); }
      *(f16x8*)((isK ? kh : qh) + row * D_ + e * 8) = hv;
      if (isK) {
        float sq = x0[0]*x0[0] + x0[1]*x0[1] + x0[2]*x0[2] + x0[3]*x0[3]
                 + x1[0]*x1[0] + x1[1]*x1[1] + x1[2]*x1[2] + x1[3]*x1[3];
        sq += __shfl_xor(sq, 1); sq += __shfl_xor(sq, 2); sq += __shfl_xor(sq, 4);
        if (e == 0) {
          int b = (int)(row >> 15);
          int n = (int)(row & (N_ - 1));
          int mv = bytes_mode ? (int)((const unsigned char*)mask)[b * N_ + n]
                              : ((const int*)mask)[b * N_ + n];
          bias[row] = mv ? -1e30f : -sq * LOG2E;
        }
      }
    }
  }
}

// ---------------------------------------------------------------------------
// Main: flash attention. Swapped-operand QK^T with (bias - m) as MFMA C-in
// so scores arrive already max-shifted. Per-lane fast-path test (no cross-
// lane ops in the common case); l-reduction deferred to epilogue; iteration
// 0 peeled to establish m. Block = 4 waves x 16 q-rows. LDS 40KB -> 4 blk/CU.
// ---------------------------------------------------------------------------
__global__ __launch_bounds__(256, 4) void attend_main(
    const f16* __restrict__ qh, const f16* __restrict__ kh,
    const f16* __restrict__ vt, const float* __restrict__ bias,
    float* __restrict__ out) {
  __shared__ f16 Kt[2][4096];
  __shared__ f16 Vt[2][4096];
  __shared__ f16 Pb[4][1024];

  int tid = threadIdx.x;
  int w = tid >> 6, lane = tid & 63;
  int j = lane & 15, g = lane >> 4;

  int bid = (blockIdx.x & 7) * 128 + (blockIdx.x >> 3);
  int head = bid >> 5;
  int qt = bid & 31;
  int qrow0 = qt * 64 + w * 16;
  int off = ((bid >> 5) & 3) * 8;          // co-resident blocks differ in phase

  const f16* qbase = qh + ((long)head * N_ + qrow0 + j) * D_;
  f16x8 qf0 = *(const f16x8*)(qbase + g * 8);
  f16x8 qf1 = *(const f16x8*)(qbase + 32 + g * 8);

  const char* kg = (const char*)(kh + (long)head * N_ * D_);
  const char* vg = (const char*)(vt + (long)head * D_ * N_);
  const float* bb = bias + (long)head * N_ + g * 4;

  int ko0[4], ko1[4];
#pragma unroll
  for (int x = 0; x < 4; ++x) {
    int rk = x * 16 + j;
    int swk = (rk & 7) << 4;
    ko0[x] = ((rk << 7) + g * 16) ^ swk;
    ko1[x] = ((rk << 7) + 64 + g * 16) ^ swk;
  }
  int pswz = (j & 7) << 4;
  int pw0 = ((j << 7) + g * 8) ^ pswz;
  int pr0 = ((j << 7) + g * 16) ^ pswz;
  int pr1 = ((j << 7) + 64 + g * 16) ^ pswz;

  f32x4 O0 = {0.f,0.f,0.f,0.f}, O1 = {0.f,0.f,0.f,0.f};
  f32x4 O2 = {0.f,0.f,0.f,0.f}, O3 = {0.f,0.f,0.f,0.f};
  float m = -1e30f, l = 0.f;     // per-lane; l reduced only at epilogue

  auto stage = [&](int buf, int t) {
    int kv = t * KVB;
    if (w < 2) {
      const char* src = kg + (size_t)kv * 128;
      char* lb = (char*)&Kt[buf][0];
#pragma unroll
      for (int c = 0; c < 4; ++c) {
        int chunk = w * 4 + c;
        int o = chunk * 1024 + lane * 16;
        int p = o ^ (((o >> 7) & 7) << 4);
        gl_lds16(src + p, lb + chunk * 1024);
      }
    } else {
      const char* src = vg + (size_t)kv * 2;
      char* lb = (char*)&Vt[buf][0];
#pragma unroll
      for (int c = 0; c < 4; ++c) {
        int chunk = (w - 2) * 4 + c;
        int o = chunk * 1024 + lane * 16;
        int p = o ^ (((o >> 7) & 7) << 4);
        gl_lds16(src + (size_t)(p >> 7) * (N_ * 2) + (p & 127), lb + chunk * 1024);
      }
    }
  };

  // helper macros as lambdas -------------------------------------------------
  auto qkt = [&](const char* Kc, f32x4* sA, const f32x4* cin) {
    __builtin_amdgcn_s_setprio(1);
#pragma unroll
    for (int jt = 0; jt < 4; ++jt) {
      f16x8 k0 = *(const f16x8*)(Kc + ko0[jt]);
      f16x8 k1 = *(const f16x8*)(Kc + ko1[jt]);
      f32x4 a = __builtin_amdgcn_mfma_f32_16x16x32_f16(k0, qf0, cin[jt], 0, 0, 0);
      sA[jt]  = __builtin_amdgcn_mfma_f32_16x16x32_f16(k1, qf1, a, 0, 0, 0);
    }
    __builtin_amdgcn_s_setprio(0);
  };
  auto finish_pv = [&](const char* Vc, const f32x4* sA) {
    // exp2 (inputs already max-shifted), pack, per-lane row-sum, P->LDS, PV
    f16x2 pk[8];
    float rsum = 0.f;
    const f16x2 ones = {(f16)1.0f, (f16)1.0f};
#pragma unroll
    for (int jt = 0; jt < 4; ++jt) {
      float p0 = __builtin_amdgcn_exp2f(sA[jt][0]);
      float p1 = __builtin_amdgcn_exp2f(sA[jt][1]);
      float p2 = __builtin_amdgcn_exp2f(sA[jt][2]);
      float p3 = __builtin_amdgcn_exp2f(sA[jt][3]);
      pk[jt * 2 + 0] = cvt_pk(p0, p1);
      pk[jt * 2 + 1] = cvt_pk(p2, p3);
      rsum = dot2acc(pk[jt * 2 + 0], ones, rsum);
      rsum = dot2acc(pk[jt * 2 + 1], ones, rsum);
    }
    l += rsum;                          // per-lane partial; no shuffles here
    char* Pw = (char*)&Pb[w][0];
#pragma unroll
    for (int jt = 0; jt < 4; ++jt) {
      f16x4 pv_ = __builtin_shufflevector(pk[jt * 2], pk[jt * 2 + 1], 0, 1, 2, 3);
      *(f16x4*)(Pw + (pw0 ^ (jt * 32))) = pv_;
    }
    f16x8 pf0 = *(const f16x8*)(Pw + pr0);
    f16x8 pf1 = *(const f16x8*)(Pw + pr1);
    __builtin_amdgcn_s_setprio(1);
#pragma unroll
    for (int dt = 0; dt < 4; ++dt) {
      f16x8 v0 = *(const f16x8*)(Vc + ko0[dt]);
      f16x8 v1 = *(const f16x8*)(Vc + ko1[dt]);
      f32x4* Od = (dt == 0) ? &O0 : (dt == 1) ? &O1 : (dt == 2) ? &O2 : &O3;
      *Od = __builtin_amdgcn_mfma_f32_16x16x32_f16(pf0, v0, *Od, 0, 0, 0);
      *Od = __builtin_amdgcn_mfma_f32_16x16x32_f16(pf1, v1, *Od, 0, 0, 0);
    }
    __builtin_amdgcn_s_setprio(0);
  };
  auto lane_max16 = [&](const f32x4* sA) {
    float a0 = fmaxf(fmaxf(sA[0][0], sA[0][1]), fmaxf(sA[0][2], sA[0][3]));
    float a1 = fmaxf(fmaxf(sA[1][0], sA[1][1]), fmaxf(sA[1][2], sA[1][3]));
    float a2 = fmaxf(fmaxf(sA[2][0], sA[2][1]), fmaxf(sA[2][2], sA[2][3]));
    float a3 = fmaxf(fmaxf(sA[3][0], sA[3][1]), fmaxf(sA[3][2], sA[3][3]));
    return fmaxf(fmaxf(a0, a1), fmaxf(a2, a3));
  };

  f32x4 bnx[4];                         // raw bias of CURRENT tile
#pragma unroll
  for (int jt = 0; jt < 4; ++jt) bnx[jt] = *(const f32x4*)(bb + off * KVB + jt * 16);

  stage(0, off);
  __syncthreads();
  int cur = 0;

  // ---- peeled iteration 0: establish m with raw-bias scores (exact f32
  // -1e30-absorption semantics for masked keys, as in R4-R7) ----
  {
    int tn = (off + 1) & (NT - 1);
    stage(1, tn);
    f32x4 sA[4];
    qkt((const char*)&Kt[0][0], sA, bnx);
#pragma unroll
    for (int jt = 0; jt < 4; ++jt) bnx[jt] = *(const f32x4*)(bb + tn * KVB + jt * 16);

    float tm = lane_max16(sA);
    tm = fmaxf(tm, __shfl_xor(tm, 16));
    tm = fmaxf(tm, __shfl_xor(tm, 32));
    m = fmaxf(m, tm);                   // = row max (real scale)
#pragma unroll
    for (int jt = 0; jt < 4; ++jt)
#pragma unroll
      for (int r = 0; r < 4; ++r) sA[jt][r] -= m;
    finish_pv((const char*)&Vt[0][0], sA);
    __syncthreads();
    cur = 1;
  }

  for (int t = 1; t < NT; ++t) {
    int tt = (t + off) & (NT - 1);
    int tn = (tt + 1) & (NT - 1);

    // C-init = bias - m (computed off the serial chain, overlaps staging)
    f32x4 madj[4];
#pragma unroll
    for (int jt = 0; jt < 4; ++jt) {
      madj[jt][0] = bnx[jt][0] - m; madj[jt][1] = bnx[jt][1] - m;
      madj[jt][2] = bnx[jt][2] - m; madj[jt][3] = bnx[jt][3] - m;
    }
    if (t + 1 < NT) stage(cur ^ 1, tn);

    f32x4 sA[4];
    qkt((const char*)&Kt[cur][0], sA, madj);   // sA = s - m directly

    if (t + 1 < NT) {
#pragma unroll
      for (int jt = 0; jt < 4; ++jt)
        bnx[jt] = *(const f32x4*)(bb + tn * KVB + jt * 16);
    }

    // ---- per-lane fast-path test: no cross-lane ops unless max grew ----
    float tmL = lane_max16(sA);          // lane's max of (s - m)
    if (!__all(tmL <= 8.0f)) {
      float tmr = fmaxf(tmL, __shfl_xor(tmL, 16));
      tmr = fmaxf(tmr, __shfl_xor(tmr, 32));
      float delta = fmaxf(tmr, 0.0f);    // row-uniform max growth
      float sc = __builtin_amdgcn_exp2f(-delta);
      m += delta;
      l *= sc;
#pragma unroll
      for (int r = 0; r < 4; ++r) {
        float scr = __shfl(sc, g * 4 + r);
        O0[r] *= scr; O1[r] *= scr; O2[r] *= scr; O3[r] *= scr;
      }
#pragma unroll
      for (int jt = 0; jt < 4; ++jt)
#pragma unroll
        for (int r = 0; r < 4; ++r) sA[jt][r] -= delta;
    }

    finish_pv((const char*)&Vt[cur][0], sA);
    __syncthreads();
    cur ^= 1;
  }

  // ---- epilogue: reduce l across the row's 4 lanes, then normalize ----
  l += __shfl_xor(l, 16);
  l += __shfl_xor(l, 32);
  float* ob = out + ((long)head * N_ + qrow0 + g * 4) * D_ + j;
#pragma unroll
  for (int r = 0; r < 4; ++r) {
    float inv = 1.0f / __shfl(l, g * 4 + r);
    float* o2 = ob + (long)r * D_;
    o2[0]  = O0[r] * inv;
    o2[16] = O1[r] * inv;
    o2[32] = O2[r] * inv;
    o2[48] = O3[r] * inv;
  }
}

extern "C" void kernel_launch(void* const* d_in, const int* in_sizes, int n_in,
                              void* d_out, int out_size, void* d_ws, size_t ws_size,
                              hipStream_t stream) {
  const float* q = (const float*)d_in[0];
  const float* k = (const float*)d_in[1];
  const float* v = (const float*)d_in[2];
  const void* mask = d_in[3];

  char* ws = (char*)d_ws;
  f16*   qh   = (f16*)ws;
  f16*   kh   = (f16*)(ws + (8u  << 20));
  f16*   vt   = (f16*)(ws + (16u << 20));
  float* bias = (float*)(ws + (24u << 20));
  float* out  = (float*)d_out;

  prep_all<<<dim3(2048), dim3(256), 0, stream>>>(q, k, v, mask, qh, kh, vt, bias);
  attend_main<<<dim3(NH_ * (N_ / 64)), dim3(256), 0, stream>>>(qh, kh, vt, bias, out);
}